// Round 6
// baseline (101.633 us; speedup 1.0000x reference)
//
#include <hip/hip_runtime.h>

// out[b] = sum_h (x @ W^T)[b,h] * 1.0  ==  dot(x[b,:], colsum_h(W))
// Phase 1: partial column sums of W. 1024 blocks (4/CU, 16 waves/CU).
// Phase 2: wide reduce of 256 partials -> wsum (64 blocks, ~2 us).
// Phase 3: matvec: 4096 blocks, LDS wsum, TWO rows interleaved per wave
//          (two independent load chains -> 2x memory-level parallelism,
//          reduce of row A hides under loads of row B).

#define BATCH   32768
#define HIDDEN  4096
#define INDIM   4096
#define ROWCHUNKS 256
#define ROWS_PER_CHUNK (HIDDEN / ROWCHUNKS)   // 16

typedef float f32x4 __attribute__((ext_vector_type(4)));

// ---------------------------------------------------------------------------
// Kernel 1: partial column sums. grid (4, 256), block 256 -> 1024 blocks.
// Thread owns one float4 column-group, sums 16 rows.
__global__ void __launch_bounds__(256)
colsum_partial_kernel(const float* __restrict__ W, float* __restrict__ partial) {
    const int col4 = blockIdx.x * 256 + threadIdx.x;      // 0..1023
    const int row0 = blockIdx.y * ROWS_PER_CHUNK;
    const f32x4* Wv = reinterpret_cast<const f32x4*>(W);
    f32x4 acc = {0.f, 0.f, 0.f, 0.f};
#pragma unroll 16
    for (int r = 0; r < ROWS_PER_CHUNK; ++r) {
        f32x4 v = Wv[(size_t)(row0 + r) * (INDIM / 4) + col4];
        acc += v;
    }
    reinterpret_cast<f32x4*>(partial)[(size_t)blockIdx.y * (INDIM / 4) + col4] = acc;
}

// ---------------------------------------------------------------------------
// Kernel 2: wide reduce: 64 blocks x 256 threads, block owns 64 columns.
// Wave w sums chunks [w*64, (w+1)*64); lanes read 256 B contiguous per step.
// Cross-wave reduce via 1 KiB LDS. Fixed order -> deterministic.
__global__ void __launch_bounds__(256)
colsum_final_kernel(const float* __restrict__ partial, float* __restrict__ wsum) {
    __shared__ float red[4][64];
    const int t    = threadIdx.x;
    const int lane = t & 63;
    const int wave = t >> 6;
    const int col  = blockIdx.x * 64 + lane;
    float acc = 0.f;
#pragma unroll 8
    for (int p = 0; p < ROWCHUNKS / 4; ++p)               // 64 chunks per wave
        acc += partial[(size_t)(wave * (ROWCHUNKS / 4) + p) * INDIM + col];
    red[wave][lane] = acc;
    __syncthreads();
    if (wave == 0)
        wsum[col] = (red[0][lane] + red[1][lane]) + (red[2][lane] + red[3][lane]);
}

// ---------------------------------------------------------------------------
// Kernel 3: matvec, 4096 blocks x 256 threads = 16384 waves, 2 rows per wave
// interleaved in the k-loop. Block covers 8 consecutive rows (128 KiB span).
__global__ void __launch_bounds__(256)
matvec_kernel(const float* __restrict__ x, const float* __restrict__ wsum,
              float* __restrict__ out) {
    __shared__ f32x4 wlds[INDIM / 4];                     // 16 KiB
    const int tid = threadIdx.x;
    const f32x4* wv = reinterpret_cast<const f32x4*>(wsum);
#pragma unroll
    for (int j = 0; j < 4; ++j)
        wlds[j * 256 + tid] = wv[j * 256 + tid];
    __syncthreads();

    const int lane = tid & 63;
    const int wid  = blockIdx.x * 4 + (tid >> 6);         // 0..16383
    const size_t rowA = (size_t)wid * 2;
    const size_t rowB = rowA + 1;
    const f32x4* xa = reinterpret_cast<const f32x4*>(x) + rowA * (INDIM / 4);
    const f32x4* xb = reinterpret_cast<const f32x4*>(x) + rowB * (INDIM / 4);

    float acc0 = 0.f, acc1 = 0.f;
#pragma unroll
    for (int k = 0; k < INDIM / 4 / 64; ++k) {            // 16 steps
        const int idx = k * 64 + lane;
        f32x4 a = __builtin_nontemporal_load(&xa[idx]);   // independent chain A
        f32x4 b = __builtin_nontemporal_load(&xb[idx]);   // independent chain B
        f32x4 w = wlds[idx];
        acc0 += a.x * w.x + a.y * w.y + a.z * w.z + a.w * w.w;
        acc1 += b.x * w.x + b.y * w.y + b.z * w.z + b.w * w.w;
    }

#pragma unroll
    for (int off = 32; off > 0; off >>= 1) {
        acc0 += __shfl_down(acc0, off, 64);
        acc1 += __shfl_down(acc1, off, 64);
    }

    if (lane == 0) {
        out[rowA] = acc0 * 1.0f;   // COMBINED_SCALE = 2.0/2.0
        out[rowB] = acc1 * 1.0f;
    }
}

// ---------------------------------------------------------------------------
extern "C" void kernel_launch(void* const* d_in, const int* in_sizes, int n_in,
                              void* d_out, int out_size, void* d_ws, size_t ws_size,
                              hipStream_t stream) {
    const float* x = (const float*)d_in[0];        // (32768, 4096)
    const float* W = (const float*)d_in[1];        // (4096, 4096)
    float* out = (float*)d_out;                    // 32768 floats

    float* partial = (float*)d_ws;                               // 4 MiB
    float* wsum    = partial + (size_t)ROWCHUNKS * INDIM;        // 16 KiB

    colsum_partial_kernel<<<dim3(INDIM / 4 / 256, ROWCHUNKS), 256, 0, stream>>>(W, partial);
    colsum_final_kernel<<<dim3(INDIM / 64), 256, 0, stream>>>(partial, wsum);
    matvec_kernel<<<dim3(BATCH / 8), 256, 0, stream>>>(x, wsum, out);
}